// Round 13
// baseline (2097.154 us; speedup 1.0000x reference)
//
#include <hip/hip_runtime.h>

constexpr int D = 1024;   // d_model
constexpr int S = 1024;   // seq len
constexpr int NB = 4;     // batch
constexpr int NH = 16;    // heads
constexpr int DK = 64;    // head dim
constexpr float THRESH = 0.019f;
constexpr int ROWS = 8;   // q-rows per attention block
constexpr int SSP = 1044; // padded score row: stride = 261 chunks ≡ 5 mod 8
                          // -> PV A-frag reads (8 ss rows per 16 lanes) land on
                          // all 8 bank quads

typedef __attribute__((ext_vector_type(8))) short bf16x8;
typedef __attribute__((ext_vector_type(4))) float f32x4;

__device__ __forceinline__ float wave_max(float v) {
#pragma unroll
    for (int off = 32; off >= 1; off >>= 1)
        v = fmaxf(v, __shfl_xor(v, off, 64));
    return v;
}
__device__ __forceinline__ float wave_sum(float v) {
#pragma unroll
    for (int off = 32; off >= 1; off >>= 1)
        v += __shfl_xor(v, off, 64);
    return v;
}

__device__ __forceinline__ int cvtpk(float lo, float hi) {
    int r;
    asm("v_cvt_pk_bf16_f32 %0, %1, %2" : "=v"(r) : "v"(lo), "v"(hi));
    return r;
}
__device__ __forceinline__ bf16x8 pack_bf8(float4 a, float4 b) {
    union { int i[4]; bf16x8 v; } u;
    u.i[0] = cvtpk(a.x, a.y);
    u.i[1] = cvtpk(a.z, a.w);
    u.i[2] = cvtpk(b.x, b.y);
    u.i[3] = cvtpk(b.z, b.w);
    return u.v;
}

// FUSED Q/K f32 projection + V bf16-MFMA projection. QK scores must be f32
// end-to-end (R1/R7/R12: every approximation — log-cutoff, 2-term split,
// 3-term split — flips the sharp-mask boundary). V-in-bf16 proven (R4..R11).
// Fusion lesson from R10: only fuse when BOTH paths fit the same VGPR
// budget. R11's V path needs ~90 VGPR < f32 path's ~116, enforced via
// __launch_bounds__(256,4) (<=128 VGPR, 4 blocks/CU). Parity-interleaved
// bids co-locate latency-bound V blocks with VALU-stall-bound f32 blocks;
// LDS 33.8KB -> 4 blocks/CU -> all 1024 blocks co-resident.
// Both path bodies are R11-VERBATIM (bit-identical numerics).
__global__ __launch_bounds__(256, 4) void proj_fused(
    const float* __restrict__ Qi, const float* __restrict__ Ki, const float* __restrict__ Vi,
    const float* __restrict__ Wq, const float* __restrict__ bq,
    const float* __restrict__ Wk, const float* __restrict__ bk,
    const float* __restrict__ Wv, const float* __restrict__ bv,
    float* __restrict__ qo, float* __restrict__ ko, float* __restrict__ vo)
{
    __shared__ __align__(16) union SM {
        struct { float Xs[2][16][132]; float Ws[2][16][132]; } f;   // 33.8 KB
        struct { short Ah[128][40];    short Bh[64][40];     } v;   // 15.0 KB
    } sm;

    const int bid = blockIdx.x;
    const int t   = threadIdx.x;

    if ((bid & 1) == 0) {
        // ============ f32 Q/K path (R11 proj_kernel, verbatim) ============
        const int fix = bid >> 1;                // 0..511
        const int pz  = fix >> 8;                // 0 = Q, 1 = K
        const int rb  = fix & 255;
        const int n0  = (rb & 7) * 128;
        const int m0  = (rb >> 3) * 128;

        const float* __restrict__ X    = (pz == 0) ? Qi : Ki;
        const float* __restrict__ W    = (pz == 0) ? Wq : Wk;
        const float* __restrict__ bias = (pz == 0) ? bq : bk;

        const int tx = t & 15;          // n: cols {4tx..4tx+3, 64+4tx..+3}
        const int ty = t >> 4;          // m: rows {4ty..4ty+3, 64+4ty..+3}
        const int lr = t >> 1;          // staging row 0..127
        const int lc = (t & 1) << 3;    // staging col 0 or 8

        const float* __restrict__ Xp = X + (size_t)(m0 + lr) * D + lc;
        const float* __restrict__ Wp = W + (size_t)(n0 + lr) * D + lc;

        float4 xa = *(const float4*)(Xp + 0);
        float4 xb = *(const float4*)(Xp + 4);
        float4 wa = *(const float4*)(Wp + 0);
        float4 wb = *(const float4*)(Wp + 4);
        sm.f.Xs[0][lc + 0][lr] = xa.x; sm.f.Xs[0][lc + 1][lr] = xa.y; sm.f.Xs[0][lc + 2][lr] = xa.z; sm.f.Xs[0][lc + 3][lr] = xa.w;
        sm.f.Xs[0][lc + 4][lr] = xb.x; sm.f.Xs[0][lc + 5][lr] = xb.y; sm.f.Xs[0][lc + 6][lr] = xb.z; sm.f.Xs[0][lc + 7][lr] = xb.w;
        sm.f.Ws[0][lc + 0][lr] = wa.x; sm.f.Ws[0][lc + 1][lr] = wa.y; sm.f.Ws[0][lc + 2][lr] = wa.z; sm.f.Ws[0][lc + 3][lr] = wa.w;
        sm.f.Ws[0][lc + 4][lr] = wb.x; sm.f.Ws[0][lc + 5][lr] = wb.y; sm.f.Ws[0][lc + 6][lr] = wb.z; sm.f.Ws[0][lc + 7][lr] = wb.w;
        __syncthreads();

        float acc[8][8] = {};           // [i: row frag][j: col frag]
        int buf = 0;

        for (int k0 = 0; k0 < D; k0 += 16) {
            const bool more = (k0 + 16) < D;
            if (more) {
                xa = *(const float4*)(Xp + k0 + 16);
                xb = *(const float4*)(Xp + k0 + 20);
                wa = *(const float4*)(Wp + k0 + 16);
                wb = *(const float4*)(Wp + k0 + 20);
            }
#pragma unroll
            for (int kk = 0; kk < 16; ++kk) {
                float4 a0 = *(const float4*)&sm.f.Xs[buf][kk][(ty << 2)];
                float4 a1 = *(const float4*)&sm.f.Xs[buf][kk][64 + (ty << 2)];
                float4 b0 = *(const float4*)&sm.f.Ws[buf][kk][(tx << 2)];
                float4 b1 = *(const float4*)&sm.f.Ws[buf][kk][64 + (tx << 2)];
                float av[8]  = {a0.x, a0.y, a0.z, a0.w, a1.x, a1.y, a1.z, a1.w};
                float bv8[8] = {b0.x, b0.y, b0.z, b0.w, b1.x, b1.y, b1.z, b1.w};
#pragma unroll
                for (int i = 0; i < 8; ++i)
#pragma unroll
                    for (int j = 0; j < 8; ++j)
                        acc[i][j] += av[i] * bv8[j];
            }
            if (more) {
                const int nb = buf ^ 1;
                sm.f.Xs[nb][lc + 0][lr] = xa.x; sm.f.Xs[nb][lc + 1][lr] = xa.y; sm.f.Xs[nb][lc + 2][lr] = xa.z; sm.f.Xs[nb][lc + 3][lr] = xa.w;
                sm.f.Xs[nb][lc + 4][lr] = xb.x; sm.f.Xs[nb][lc + 5][lr] = xb.y; sm.f.Xs[nb][lc + 6][lr] = xb.z; sm.f.Xs[nb][lc + 7][lr] = xb.w;
                sm.f.Ws[nb][lc + 0][lr] = wa.x; sm.f.Ws[nb][lc + 1][lr] = wa.y; sm.f.Ws[nb][lc + 2][lr] = wa.z; sm.f.Ws[nb][lc + 3][lr] = wa.w;
                sm.f.Ws[nb][lc + 4][lr] = wb.x; sm.f.Ws[nb][lc + 5][lr] = wb.y; sm.f.Ws[nb][lc + 6][lr] = wb.z; sm.f.Ws[nb][lc + 7][lr] = wb.w;
                __syncthreads();
                buf = nb;
            }
        }

        const int bb2 = m0 >> 10;
        if (pz == 1) {
            // kT[((b*NH+h)*DK + d)*S + s], float4 along s
            const int s_base = (m0 & 1023) + (ty << 2);
#pragma unroll
            for (int g = 0; g < 2; ++g) {
                const int hh = (n0 >> 6) + g;
#pragma unroll
                for (int jj = 0; jj < 4; ++jj) {
                    const int d = (tx << 2) + jj;
                    const int j = (g << 2) + jj;
                    const float bj = bias[n0 + (g << 6) + d];
                    float* op = &ko[(((size_t)bb2 * NH + hh) * DK + d) * S];
                    *(float4*)(op + s_base) =
                        make_float4(acc[0][j] + bj, acc[1][j] + bj, acc[2][j] + bj, acc[3][j] + bj);
                    *(float4*)(op + s_base + 64) =
                        make_float4(acc[4][j] + bj, acc[5][j] + bj, acc[6][j] + bj, acc[7][j] + bj);
                }
            }
        } else {
            float bj[8];
#pragma unroll
            for (int j = 0; j < 8; ++j)
                bj[j] = bias[n0 + ((j >> 2) << 6) + (tx << 2) + (j & 3)];
#pragma unroll
            for (int i = 0; i < 8; ++i) {
                const int sr = (m0 & 1023) + ((i >> 2) << 6) + (ty << 2) + (i & 3);
#pragma unroll
                for (int g = 0; g < 2; ++g) {
                    const int hh = (n0 >> 6) + g;
                    float* op = &qo[(((size_t)bb2 * NH + hh) * S + sr) * DK + (tx << 2)];
                    *(float4*)op = make_float4(acc[i][(g << 2) + 0] + bj[(g << 2) + 0],
                                               acc[i][(g << 2) + 1] + bj[(g << 2) + 1],
                                               acc[i][(g << 2) + 2] + bj[(g << 2) + 2],
                                               acc[i][(g << 2) + 3] + bj[(g << 2) + 3]);
                }
            }
        }
    } else {
        // ============ V path (R11 vproj_kernel, verbatim) ============
        const int vix = bid >> 1;                // 0..511
        const int n0  = (vix & 15) * 64;
        const int m0  = (vix >> 4) * 128;

        const int lane = t & 63;
        const int w    = t >> 6;
        const int wm   = w >> 1;        // wave rows 64*wm..+63
        const int wn   = w & 1;         // wave cols 32*wn..+31
        const int cr   = lane & 15;
        const int gq   = lane >> 4;

        const int ar = t >> 1, ha = (t & 1) * 16;
        const int br = t >> 2, bq2 = (t & 3) * 8;
        const float* __restrict__ Ap = Vi + (size_t)(m0 + ar) * D + ha;
        const float* __restrict__ Bp = Wv + (size_t)(n0 + br) * D + bq2;

        float4 a0 = *(const float4*)(Ap + 0),  a1 = *(const float4*)(Ap + 4);
        float4 a2 = *(const float4*)(Ap + 8),  a3 = *(const float4*)(Ap + 12);
        float4 b0 = *(const float4*)(Bp + 0),  b1 = *(const float4*)(Bp + 4);

        f32x4 acc[4][2];
#pragma unroll
        for (int mi = 0; mi < 4; ++mi)
#pragma unroll
            for (int nj = 0; nj < 2; ++nj)
                acc[mi][nj] = (f32x4){0.f, 0.f, 0.f, 0.f};

        for (int ks = 0; ks < 32; ++ks) {
            *(int4*)&sm.v.Ah[ar][ha + 0] = make_int4(cvtpk(a0.x, a0.y), cvtpk(a0.z, a0.w),
                                                     cvtpk(a1.x, a1.y), cvtpk(a1.z, a1.w));
            *(int4*)&sm.v.Ah[ar][ha + 8] = make_int4(cvtpk(a2.x, a2.y), cvtpk(a2.z, a2.w),
                                                     cvtpk(a3.x, a3.y), cvtpk(a3.z, a3.w));
            *(int4*)&sm.v.Bh[br][bq2]    = make_int4(cvtpk(b0.x, b0.y), cvtpk(b0.z, b0.w),
                                                     cvtpk(b1.x, b1.y), cvtpk(b1.z, b1.w));
            __syncthreads();
            if (ks < 31) {   // next-step prefetch hides under frag reads + MFMA
                a0 = *(const float4*)(Ap + (ks + 1) * 32 + 0);
                a1 = *(const float4*)(Ap + (ks + 1) * 32 + 4);
                a2 = *(const float4*)(Ap + (ks + 1) * 32 + 8);
                a3 = *(const float4*)(Ap + (ks + 1) * 32 + 12);
                b0 = *(const float4*)(Bp + (ks + 1) * 32 + 0);
                b1 = *(const float4*)(Bp + (ks + 1) * 32 + 4);
            }
            bf16x8 af[4];
#pragma unroll
            for (int mi = 0; mi < 4; ++mi)
                af[mi] = *(const bf16x8*)&sm.v.Ah[64 * wm + 16 * mi + cr][gq * 8];
#pragma unroll
            for (int nj = 0; nj < 2; ++nj) {
                bf16x8 bf = *(const bf16x8*)&sm.v.Bh[32 * wn + 16 * nj + cr][gq * 8];
#pragma unroll
                for (int mi = 0; mi < 4; ++mi)
                    acc[mi][nj] = __builtin_amdgcn_mfma_f32_16x16x32_bf16(af[mi], bf, acc[mi][nj], 0, 0, 0);
            }
            __syncthreads();
        }

        // m = m0+64wm+16mi+gq*4+reg ; n = n0+32wn+16nj+cr (head = n0>>6 const)
        const int bb = m0 >> 10;
        const int hh = n0 >> 6;
#pragma unroll
        for (int nj = 0; nj < 2; ++nj) {
            const int dk = 32 * wn + 16 * nj + cr;
            const float bj = bv[n0 + dk];
#pragma unroll
            for (int mi = 0; mi < 4; ++mi) {
                const int s0 = (m0 & 1023) + 64 * wm + 16 * mi + gq * 4;
#pragma unroll
                for (int reg = 0; reg < 4; ++reg)
                    vo[(((size_t)bb * NH + hh) * S + s0 + reg) * DK + dk] = acc[mi][nj][reg] + bj;
            }
        }
    }
}

// One block per (b, h, 8 q-rows). QK + mask softmax in f32 (precision-
// critical); PV via bf16 MFMA with f32 accumulate. R11-verbatim except the
// softmax keeps x[16]/e[16] in registers across the 3 passes (removes 32
// LDS reads + 16 exp per row; values bit-identical).
__global__ __launch_bounds__(256) void attn_kernel(
    const float* __restrict__ qw, const float* __restrict__ kw,
    const float* __restrict__ vw, float* __restrict__ out)
{
    __shared__ __align__(16) float ss[ROWS][SSP];   // 33.4 KB scores -> e2 weights
    __shared__ __align__(16) float qT[DK][ROWS];    //  2.0 KB q transposed, pre-scaled by 1/8
    __shared__ float rowinv[ROWS];                  // deferred softmax normalizers

    const int t    = threadIdx.x;
    const int lane = t & 63;
    const int w    = t >> 6;

    // XCD swizzle: L%8 -> contiguous work chunk of 1024 = 8 full (b,h) panels
    const int L   = blockIdx.x + (S / ROWS) * (blockIdx.y + NH * blockIdx.z);
    const int swz = (L & 7) * ((S / ROWS) * NH * NB / 8) + (L >> 3);
    const int qx  = swz & (S / ROWS - 1);
    const int h   = (swz >> 7) & (NH - 1);
    const int b   = swz >> 11;

    const size_t base = ((size_t)b * NH + h) * S * DK;
    const float* __restrict__ qp = qw + base;
    const float* __restrict__ kp = kw + base;   // kT layout: [DK][S]
    const float* __restrict__ vp = vw + base;
    const int q0 = qx * ROWS;

    // ---- stage qT[d][r] = q[q0+r][d] / 8 ----
#pragma unroll
    for (int p = 0; p < 2; ++p) {
        int e = t + 256 * p;           // 0..511
        int d = e >> 3, r = e & 7;
        qT[d][r] = qp[(size_t)(q0 + r) * DK + d] * 0.125f;
    }
    __syncthreads();

    // ---- QK: thread owns keys 4t..4t+3; kT[d][4t..4t+3] coalesced, 4-deep ring ----
    float accf[ROWS][4] = {};          // [row][key]
    const float* __restrict__ kTb = kp + 4 * t;

    float4 kbuf[4];
#pragma unroll
    for (int d = 0; d < 4; ++d)
        kbuf[d] = *(const float4*)&kTb[(size_t)d * S];

#pragma unroll
    for (int d0 = 0; d0 < DK; d0 += 4) {
        float4 kc[4] = {kbuf[0], kbuf[1], kbuf[2], kbuf[3]};
        if (d0 < DK - 4) {
#pragma unroll
            for (int d = 0; d < 4; ++d)
                kbuf[d] = *(const float4*)&kTb[(size_t)(d0 + 4 + d) * S];
        }
#pragma unroll
        for (int dd = 0; dd < 4; ++dd) {
            const int d = d0 + dd;
            float4 qa = *(const float4*)&qT[d][0];   // rows 0..3 (broadcast)
            float4 qb = *(const float4*)&qT[d][4];   // rows 4..7
            float qr[8] = {qa.x, qa.y, qa.z, qa.w, qb.x, qb.y, qb.z, qb.w};
            float k4[4] = {kc[dd].x, kc[dd].y, kc[dd].z, kc[dd].w};
#pragma unroll
            for (int r = 0; r < ROWS; ++r)
#pragma unroll
                for (int i = 0; i < 4; ++i)
                    accf[r][i] += qr[r] * k4[i];
        }
    }
#pragma unroll
    for (int r = 0; r < ROWS; ++r)
        *(float4*)&ss[r][4 * t] = make_float4(accf[r][0], accf[r][1], accf[r][2], accf[r][3]);
    __syncthreads();

    // ---- per-row: sharp softmax -> mask -> unnormalized final weights ----
    // NOTE: mask comparison kept in the EXACT form of the reference
    // ((e/zs) < THRESH with e = __expf(100(x-mx))). x and e cached in
    // registers across passes (bit-identical values, fewer LDS reads/exps).
    for (int rr = w; rr < ROWS; rr += 4) {
        float xv[16], ev[16];
        float mx = -3.4e38f;
#pragma unroll
        for (int p = 0; p < S / 64; ++p) {
            xv[p] = ss[rr][lane + 64 * p];
            mx = fmaxf(mx, xv[p]);
        }
        mx = wave_max(mx);

        float zs = 0.f;
#pragma unroll
        for (int p = 0; p < S / 64; ++p) {
            ev[p] = __expf(100.f * (xv[p] - mx));
            zs += ev[p];
        }
        zs = wave_sum(zs);

        const bool any = !((1.0f / zs) < THRESH);

        float z2 = 0.f;
#pragma unroll
        for (int p = 0; p < S / 64; ++p) {
            bool keep = !((ev[p] / zs) < THRESH);    // exactly the reference comparison
            float e2 = any ? (keep ? __expf(xv[p] - mx) : 0.f) : 1.f;
            z2 += e2;
            ss[rr][lane + 64 * p] = e2;       // store UNNORMALIZED weight
        }
        z2 = wave_sum(z2);
        if (lane == 0) rowinv[rr] = 1.0f / z2;  // normalization deferred to epilogue
    }
    __syncthreads();

    // ---- PV via bf16 MFMA: wave w owns cols 16w..16w+15, full K=1024 ----
    // A-frag: lane supplies e2 row (lane&15)&7 (rows 8..15 duplicate 0..7 and
    // only feed discarded C rows), k-chunk = (lane>>4)*8 + j. B-frag: same
    // (chunk,pos)->k map on V; C/D layout col=lane&15, row=(lane>>4)*4+reg.
    {
        const int cr = lane & 15;
        const int gq = lane >> 4;
        const float* __restrict__ vB = vp + (size_t)(gq * 8) * DK + (w * 16 + cr);
        const float* __restrict__ arow = &ss[lane & 7][gq * 8];

        float bnx[8];
#pragma unroll
        for (int jj = 0; jj < 8; ++jj) bnx[jj] = vB[(size_t)jj * DK];

        f32x4 acc4 = {0.f, 0.f, 0.f, 0.f};
#pragma unroll 4
        for (int ks = 0; ks < 32; ++ks) {
            float bcur[8];
#pragma unroll
            for (int jj = 0; jj < 8; ++jj) bcur[jj] = bnx[jj];
            if (ks < 31) {
#pragma unroll
                for (int jj = 0; jj < 8; ++jj)
                    bnx[jj] = vB[(size_t)((ks + 1) * 32 + jj) * DK];
            }
            float4 a0 = *(const float4*)&arow[ks * 32];
            float4 a1 = *(const float4*)&arow[ks * 32 + 4];
            bf16x8 af = pack_bf8(a0, a1);
            bf16x8 bf = pack_bf8(make_float4(bcur[0], bcur[1], bcur[2], bcur[3]),
                                 make_float4(bcur[4], bcur[5], bcur[6], bcur[7]));
            acc4 = __builtin_amdgcn_mfma_f32_16x16x32_bf16(af, bf, acc4, 0, 0, 0);
        }

        if (gq < 2) {
            const int dcol = h * DK + w * 16 + cr;
#pragma unroll
            for (int reg = 0; reg < 4; ++reg) {
                const int r = gq * 4 + reg;
                out[((size_t)b * S + q0 + r) * D + dcol] = acc4[reg] * rowinv[r];
            }
        }
    }
}

extern "C" void kernel_launch(void* const* d_in, const int* in_sizes, int n_in,
                              void* d_out, int out_size, void* d_ws, size_t ws_size,
                              hipStream_t stream) {
    const float* Qi = (const float*)d_in[1];
    const float* Ki = (const float*)d_in[2];
    const float* Vi = (const float*)d_in[3];
    const float* Wq = (const float*)d_in[4];
    const float* bq = (const float*)d_in[5];
    const float* Wk = (const float*)d_in[6];
    const float* bk = (const float*)d_in[7];
    const float* Wv = (const float*)d_in[8];
    const float* bv = (const float*)d_in[9];
    float* outp = (float*)d_out;

    float* qws = (float*)d_ws;                       // f32 [B,H,S,DK]
    float* kws = qws + (size_t)NB * NH * S * DK;     // f32 [B,H,DK,S] (transposed)
    float* vws = kws + (size_t)NB * NH * S * DK;     // f32 [B,H,S,DK]

    proj_fused<<<dim3(1024), 256, 0, stream>>>(Qi, Ki, Vi, Wq, bq, Wk, bk, Wv, bv,
                                               qws, kws, vws);

    dim3 g2(S / ROWS, NH, NB);
    attn_kernel<<<g2, 256, 0, stream>>>(qws, kws, vws, outp);
}

// Round 15
// 538.754 us; speedup vs baseline: 3.8926x; 3.8926x over previous
//
#include <hip/hip_runtime.h>

constexpr int D = 1024;   // d_model
constexpr int S = 1024;   // seq len
constexpr int NB = 4;     // batch
constexpr int NH = 16;    // heads
constexpr int DK = 64;    // head dim
constexpr float THRESH = 0.019f;
constexpr int ROWS = 8;   // q-rows per attention block
constexpr int SSP = 1044; // padded score row: stride = 261 chunks ≡ 5 mod 8
                          // -> PV A-frag reads (8 ss rows per 16 lanes) land on
                          // all 8 bank quads

typedef __attribute__((ext_vector_type(8))) short bf16x8;
typedef __attribute__((ext_vector_type(4))) float f32x4;

__device__ __forceinline__ float wave_max(float v) {
#pragma unroll
    for (int off = 32; off >= 1; off >>= 1)
        v = fmaxf(v, __shfl_xor(v, off, 64));
    return v;
}
__device__ __forceinline__ float wave_sum(float v) {
#pragma unroll
    for (int off = 32; off >= 1; off >>= 1)
        v += __shfl_xor(v, off, 64);
    return v;
}

__device__ __forceinline__ int cvtpk(float lo, float hi) {
    int r;
    asm("v_cvt_pk_bf16_f32 %0, %1, %2" : "=v"(r) : "v"(lo), "v"(hi));
    return r;
}
__device__ __forceinline__ bf16x8 pack_bf8(float4 a, float4 b) {
    union { int i[4]; bf16x8 v; } u;
    u.i[0] = cvtpk(a.x, a.y);
    u.i[1] = cvtpk(a.z, a.w);
    u.i[2] = cvtpk(b.x, b.y);
    u.i[3] = cvtpk(b.z, b.w);
    return u.v;
}

// Y[m][n] = sum_k X[m][k] * W[n][k] + bias[n]  -- f32 compute, z = {Q,K}.
// R11-verbatim. QK scores must be f32 end-to-end (R1/R7/R12: log-cutoff,
// 2-term and 3-term bf16 splits all flip the sharp-mask boundary).
// NOT fused with V (R10: VGPR max-over-paths kills occupancy; R13:
// launch_bounds min-waves forces 64-VGPR spill catastrophe).
// q written head-split [B,H,S,DK]; k written TRANSPOSED [B,H,DK,S].
__global__ __launch_bounds__(256) void proj_kernel(
    const float* __restrict__ Qi, const float* __restrict__ Ki,
    const float* __restrict__ Wq, const float* __restrict__ bq,
    const float* __restrict__ Wk, const float* __restrict__ bk,
    float* __restrict__ qo, float* __restrict__ ko)
{
    const int pz = blockIdx.z;
    const float* __restrict__ X    = (pz == 0) ? Qi : Ki;
    const float* __restrict__ W    = (pz == 0) ? Wq : Wk;
    const float* __restrict__ bias = (pz == 0) ? bq : bk;

    __shared__ __align__(16) float Xs[2][16][132];
    __shared__ __align__(16) float Ws[2][16][132];

    const int t  = threadIdx.x;
    const int tx = t & 15;          // n: cols {4tx..4tx+3, 64+4tx..+3}
    const int ty = t >> 4;          // m: rows {4ty..4ty+3, 64+4ty..+3}
    const int m0 = blockIdx.y * 128;
    const int n0 = blockIdx.x * 128;
    const int lr = t >> 1;          // staging row 0..127
    const int lc = (t & 1) << 3;    // staging col 0 or 8

    const float* __restrict__ Xp = X + (size_t)(m0 + lr) * D + lc;
    const float* __restrict__ Wp = W + (size_t)(n0 + lr) * D + lc;

    // prime buffer 0
    float4 xa = *(const float4*)(Xp + 0);
    float4 xb = *(const float4*)(Xp + 4);
    float4 wa = *(const float4*)(Wp + 0);
    float4 wb = *(const float4*)(Wp + 4);
    Xs[0][lc + 0][lr] = xa.x; Xs[0][lc + 1][lr] = xa.y; Xs[0][lc + 2][lr] = xa.z; Xs[0][lc + 3][lr] = xa.w;
    Xs[0][lc + 4][lr] = xb.x; Xs[0][lc + 5][lr] = xb.y; Xs[0][lc + 6][lr] = xb.z; Xs[0][lc + 7][lr] = xb.w;
    Ws[0][lc + 0][lr] = wa.x; Ws[0][lc + 1][lr] = wa.y; Ws[0][lc + 2][lr] = wa.z; Ws[0][lc + 3][lr] = wa.w;
    Ws[0][lc + 4][lr] = wb.x; Ws[0][lc + 5][lr] = wb.y; Ws[0][lc + 6][lr] = wb.z; Ws[0][lc + 7][lr] = wb.w;
    __syncthreads();

    float acc[8][8] = {};           // [i: row frag][j: col frag]
    int buf = 0;

    for (int k0 = 0; k0 < D; k0 += 16) {
        const bool more = (k0 + 16) < D;
        if (more) {
            xa = *(const float4*)(Xp + k0 + 16);
            xb = *(const float4*)(Xp + k0 + 20);
            wa = *(const float4*)(Wp + k0 + 16);
            wb = *(const float4*)(Wp + k0 + 20);
        }
#pragma unroll
        for (int kk = 0; kk < 16; ++kk) {
            float4 a0 = *(const float4*)&Xs[buf][kk][(ty << 2)];
            float4 a1 = *(const float4*)&Xs[buf][kk][64 + (ty << 2)];
            float4 b0 = *(const float4*)&Ws[buf][kk][(tx << 2)];
            float4 b1 = *(const float4*)&Ws[buf][kk][64 + (tx << 2)];
            float av[8]  = {a0.x, a0.y, a0.z, a0.w, a1.x, a1.y, a1.z, a1.w};
            float bv8[8] = {b0.x, b0.y, b0.z, b0.w, b1.x, b1.y, b1.z, b1.w};
#pragma unroll
            for (int i = 0; i < 8; ++i)
#pragma unroll
                for (int j = 0; j < 8; ++j)
                    acc[i][j] += av[i] * bv8[j];
        }
        if (more) {
            const int nb = buf ^ 1;
            Xs[nb][lc + 0][lr] = xa.x; Xs[nb][lc + 1][lr] = xa.y; Xs[nb][lc + 2][lr] = xa.z; Xs[nb][lc + 3][lr] = xa.w;
            Xs[nb][lc + 4][lr] = xb.x; Xs[nb][lc + 5][lr] = xb.y; Xs[nb][lc + 6][lr] = xb.z; Xs[nb][lc + 7][lr] = xb.w;
            Ws[nb][lc + 0][lr] = wa.x; Ws[nb][lc + 1][lr] = wa.y; Ws[nb][lc + 2][lr] = wa.z; Ws[nb][lc + 3][lr] = wa.w;
            Ws[nb][lc + 4][lr] = wb.x; Ws[nb][lc + 5][lr] = wb.y; Ws[nb][lc + 6][lr] = wb.z; Ws[nb][lc + 7][lr] = wb.w;
            __syncthreads();
            buf = nb;
        }
    }

    // row(i) = (m0&1023) + 64*(i>>2) + 4*ty + (i&3)
    // col(j) = n0 + 64*(j>>2) + 4*tx + (j&3);  head = n0>>6 + (j>>2), d = 4*tx+(j&3)
    const int bb2 = m0 >> 10;          // batch (m0 multiple of 128; block stays in one b)
    if (pz == 1) {
        // kT[((b*NH+h)*DK + d)*S + s], float4 along s
        const int s_base = (m0 & 1023) + (ty << 2);
#pragma unroll
        for (int g = 0; g < 2; ++g) {
            const int hh = (n0 >> 6) + g;
#pragma unroll
            for (int jj = 0; jj < 4; ++jj) {
                const int d = (tx << 2) + jj;
                const int j = (g << 2) + jj;
                const float bj = bias[n0 + (g << 6) + d];
                float* op = &ko[(((size_t)bb2 * NH + hh) * DK + d) * S];
                *(float4*)(op + s_base) =
                    make_float4(acc[0][j] + bj, acc[1][j] + bj, acc[2][j] + bj, acc[3][j] + bj);
                *(float4*)(op + s_base + 64) =
                    make_float4(acc[4][j] + bj, acc[5][j] + bj, acc[6][j] + bj, acc[7][j] + bj);
            }
        }
    } else {
        float bj[8];
#pragma unroll
        for (int j = 0; j < 8; ++j)
            bj[j] = bias[n0 + ((j >> 2) << 6) + (tx << 2) + (j & 3)];
#pragma unroll
        for (int i = 0; i < 8; ++i) {
            const int sr = (m0 & 1023) + ((i >> 2) << 6) + (ty << 2) + (i & 3);
#pragma unroll
            for (int g = 0; g < 2; ++g) {
                const int hh = (n0 >> 6) + g;
                float* op = &qo[(((size_t)bb2 * NH + hh) * S + sr) * DK + (tx << 2)];
                *(float4*)op = make_float4(acc[i][(g << 2) + 0] + bj[(g << 2) + 0],
                                           acc[i][(g << 2) + 1] + bj[(g << 2) + 1],
                                           acc[i][(g << 2) + 2] + bj[(g << 2) + 2],
                                           acc[i][(g << 2) + 3] + bj[(g << 2) + 3]);
            }
        }
    }
}

// V projection via bf16 MFMA (f32 accum, f32 out [B,H,S,DK] + bias).
// R11-verbatim: 128(m) x 64(n) tile, 512 blocks, [row][40]-padded LDS,
// (chunk,pos)->k bijection identical on A and B, C/D col=lane&15
// row=gq*4+reg.
__global__ __launch_bounds__(256) void vproj_kernel(
    const float* __restrict__ Vi, const float* __restrict__ Wv,
    const float* __restrict__ bv, float* __restrict__ vo)
{
    __shared__ __align__(16) short Ah[128][40];   // 10 KB
    __shared__ __align__(16) short Bh[64][40];    //  5 KB

    const int t    = threadIdx.x;
    const int lane = t & 63;
    const int w    = t >> 6;
    const int wm   = w >> 1;        // wave rows 64*wm..+63
    const int wn   = w & 1;         // wave cols 32*wn..+31
    const int cr   = lane & 15;
    const int gq   = lane >> 4;
    const int m0   = blockIdx.y * 128;
    const int n0   = blockIdx.x * 64;

    // staging: A 128 rows x 32 k -> (row = t>>1, k-half = 16*(t&1))
    //          B  64 rows x 32 k -> (row = t>>2, k-qtr  =  8*(t&3))
    const int ar = t >> 1, ha = (t & 1) * 16;
    const int br = t >> 2, bq = (t & 3) * 8;
    const float* __restrict__ Ap = Vi + (size_t)(m0 + ar) * D + ha;
    const float* __restrict__ Bp = Wv + (size_t)(n0 + br) * D + bq;

    float4 a0 = *(const float4*)(Ap + 0),  a1 = *(const float4*)(Ap + 4);
    float4 a2 = *(const float4*)(Ap + 8),  a3 = *(const float4*)(Ap + 12);
    float4 b0 = *(const float4*)(Bp + 0),  b1 = *(const float4*)(Bp + 4);

    f32x4 acc[4][2];
#pragma unroll
    for (int mi = 0; mi < 4; ++mi)
#pragma unroll
        for (int nj = 0; nj < 2; ++nj)
            acc[mi][nj] = (f32x4){0.f, 0.f, 0.f, 0.f};

    for (int ks = 0; ks < 32; ++ks) {
        *(int4*)&Ah[ar][ha + 0] = make_int4(cvtpk(a0.x, a0.y), cvtpk(a0.z, a0.w),
                                            cvtpk(a1.x, a1.y), cvtpk(a1.z, a1.w));
        *(int4*)&Ah[ar][ha + 8] = make_int4(cvtpk(a2.x, a2.y), cvtpk(a2.z, a2.w),
                                            cvtpk(a3.x, a3.y), cvtpk(a3.z, a3.w));
        *(int4*)&Bh[br][bq]     = make_int4(cvtpk(b0.x, b0.y), cvtpk(b0.z, b0.w),
                                            cvtpk(b1.x, b1.y), cvtpk(b1.z, b1.w));
        __syncthreads();
        if (ks < 31) {   // next-step prefetch hides under frag reads + MFMA
            a0 = *(const float4*)(Ap + (ks + 1) * 32 + 0);
            a1 = *(const float4*)(Ap + (ks + 1) * 32 + 4);
            a2 = *(const float4*)(Ap + (ks + 1) * 32 + 8);
            a3 = *(const float4*)(Ap + (ks + 1) * 32 + 12);
            b0 = *(const float4*)(Bp + (ks + 1) * 32 + 0);
            b1 = *(const float4*)(Bp + (ks + 1) * 32 + 4);
        }
        bf16x8 af[4];
#pragma unroll
        for (int mi = 0; mi < 4; ++mi)
            af[mi] = *(const bf16x8*)&Ah[64 * wm + 16 * mi + cr][gq * 8];
#pragma unroll
        for (int nj = 0; nj < 2; ++nj) {
            bf16x8 bf = *(const bf16x8*)&Bh[32 * wn + 16 * nj + cr][gq * 8];
#pragma unroll
            for (int mi = 0; mi < 4; ++mi)
                acc[mi][nj] = __builtin_amdgcn_mfma_f32_16x16x32_bf16(af[mi], bf, acc[mi][nj], 0, 0, 0);
        }
        __syncthreads();
    }

    // m = m0+64wm+16mi+gq*4+reg ; n = n0+32wn+16nj+cr (head = n0>>6 const)
    const int bb = m0 >> 10;
    const int hh = n0 >> 6;
#pragma unroll
    for (int nj = 0; nj < 2; ++nj) {
        const int dk = 32 * wn + 16 * nj + cr;
        const float bj = bv[n0 + dk];
#pragma unroll
        for (int mi = 0; mi < 4; ++mi) {
            const int s0 = (m0 & 1023) + 64 * wm + 16 * mi + gq * 4;
#pragma unroll
            for (int reg = 0; reg < 4; ++reg)
                vo[(((size_t)bb * NH + hh) * S + s0 + reg) * DK + dk] = acc[mi][nj][reg] + bj;
        }
    }
}

// One block per (b, h, 8 q-rows). QK + mask softmax in f32 (precision-
// critical); PV via bf16 MFMA with f32 accumulate. R13's attn verbatim:
// softmax keeps x[16]/e[16] in registers across the 3 passes (removes 32
// LDS reads + 16 exp per row; values bit-identical to R11's pass).
__global__ __launch_bounds__(256) void attn_kernel(
    const float* __restrict__ qw, const float* __restrict__ kw,
    const float* __restrict__ vw, float* __restrict__ out)
{
    __shared__ __align__(16) float ss[ROWS][SSP];   // 33.4 KB scores -> e2 weights
    __shared__ __align__(16) float qT[DK][ROWS];    //  2.0 KB q transposed, pre-scaled by 1/8
    __shared__ float rowinv[ROWS];                  // deferred softmax normalizers

    const int t    = threadIdx.x;
    const int lane = t & 63;
    const int w    = t >> 6;

    // XCD swizzle: L%8 -> contiguous work chunk of 1024 = 8 full (b,h) panels
    const int L   = blockIdx.x + (S / ROWS) * (blockIdx.y + NH * blockIdx.z);
    const int swz = (L & 7) * ((S / ROWS) * NH * NB / 8) + (L >> 3);
    const int qx  = swz & (S / ROWS - 1);
    const int h   = (swz >> 7) & (NH - 1);
    const int b   = swz >> 11;

    const size_t base = ((size_t)b * NH + h) * S * DK;
    const float* __restrict__ qp = qw + base;
    const float* __restrict__ kp = kw + base;   // kT layout: [DK][S]
    const float* __restrict__ vp = vw + base;
    const int q0 = qx * ROWS;

    // ---- stage qT[d][r] = q[q0+r][d] / 8 ----
#pragma unroll
    for (int p = 0; p < 2; ++p) {
        int e = t + 256 * p;           // 0..511
        int d = e >> 3, r = e & 7;
        qT[d][r] = qp[(size_t)(q0 + r) * DK + d] * 0.125f;
    }
    __syncthreads();

    // ---- QK: thread owns keys 4t..4t+3; kT[d][4t..4t+3] coalesced, 4-deep ring ----
    float accf[ROWS][4] = {};          // [row][key]
    const float* __restrict__ kTb = kp + 4 * t;

    float4 kbuf[4];
#pragma unroll
    for (int d = 0; d < 4; ++d)
        kbuf[d] = *(const float4*)&kTb[(size_t)d * S];

#pragma unroll
    for (int d0 = 0; d0 < DK; d0 += 4) {
        float4 kc[4] = {kbuf[0], kbuf[1], kbuf[2], kbuf[3]};
        if (d0 < DK - 4) {
#pragma unroll
            for (int d = 0; d < 4; ++d)
                kbuf[d] = *(const float4*)&kTb[(size_t)(d0 + 4 + d) * S];
        }
#pragma unroll
        for (int dd = 0; dd < 4; ++dd) {
            const int d = d0 + dd;
            float4 qa = *(const float4*)&qT[d][0];   // rows 0..3 (broadcast)
            float4 qb = *(const float4*)&qT[d][4];   // rows 4..7
            float qr[8] = {qa.x, qa.y, qa.z, qa.w, qb.x, qb.y, qb.z, qb.w};
            float k4[4] = {kc[dd].x, kc[dd].y, kc[dd].z, kc[dd].w};
#pragma unroll
            for (int r = 0; r < ROWS; ++r)
#pragma unroll
                for (int i = 0; i < 4; ++i)
                    accf[r][i] += qr[r] * k4[i];
        }
    }
#pragma unroll
    for (int r = 0; r < ROWS; ++r)
        *(float4*)&ss[r][4 * t] = make_float4(accf[r][0], accf[r][1], accf[r][2], accf[r][3]);
    __syncthreads();

    // ---- per-row: sharp softmax -> mask -> unnormalized final weights ----
    // NOTE: mask comparison kept in the EXACT form of the reference
    // ((e/zs) < THRESH with e = __expf(100(x-mx))). x and e cached in
    // registers across passes (bit-identical values, fewer LDS reads/exps).
    for (int rr = w; rr < ROWS; rr += 4) {
        float xv[16], ev[16];
        float mx = -3.4e38f;
#pragma unroll
        for (int p = 0; p < S / 64; ++p) {
            xv[p] = ss[rr][lane + 64 * p];
            mx = fmaxf(mx, xv[p]);
        }
        mx = wave_max(mx);

        float zs = 0.f;
#pragma unroll
        for (int p = 0; p < S / 64; ++p) {
            ev[p] = __expf(100.f * (xv[p] - mx));
            zs += ev[p];
        }
        zs = wave_sum(zs);

        const bool any = !((1.0f / zs) < THRESH);

        float z2 = 0.f;
#pragma unroll
        for (int p = 0; p < S / 64; ++p) {
            bool keep = !((ev[p] / zs) < THRESH);    // exactly the reference comparison
            float e2 = any ? (keep ? __expf(xv[p] - mx) : 0.f) : 1.f;
            z2 += e2;
            ss[rr][lane + 64 * p] = e2;       // store UNNORMALIZED weight
        }
        z2 = wave_sum(z2);
        if (lane == 0) rowinv[rr] = 1.0f / z2;  // normalization deferred to epilogue
    }
    __syncthreads();

    // ---- PV via bf16 MFMA: wave w owns cols 16w..16w+15, full K=1024 ----
    // A-frag: lane supplies e2 row (lane&15)&7 (rows 8..15 duplicate 0..7 and
    // only feed discarded C rows), k-chunk = (lane>>4)*8 + j. B-frag: same
    // (chunk,pos)->k map on V; C/D layout col=lane&15, row=(lane>>4)*4+reg.
    {
        const int cr = lane & 15;
        const int gq = lane >> 4;
        const float* __restrict__ vB = vp + (size_t)(gq * 8) * DK + (w * 16 + cr);
        const float* __restrict__ arow = &ss[lane & 7][gq * 8];

        float bnx[8];
#pragma unroll
        for (int jj = 0; jj < 8; ++jj) bnx[jj] = vB[(size_t)jj * DK];

        f32x4 acc4 = {0.f, 0.f, 0.f, 0.f};
#pragma unroll 4
        for (int ks = 0; ks < 32; ++ks) {
            float bcur[8];
#pragma unroll
            for (int jj = 0; jj < 8; ++jj) bcur[jj] = bnx[jj];
            if (ks < 31) {
#pragma unroll
                for (int jj = 0; jj < 8; ++jj)
                    bnx[jj] = vB[(size_t)((ks + 1) * 32 + jj) * DK];
            }
            float4 a0 = *(const float4*)&arow[ks * 32];
            float4 a1 = *(const float4*)&arow[ks * 32 + 4];
            bf16x8 af = pack_bf8(a0, a1);
            bf16x8 bf = pack_bf8(make_float4(bcur[0], bcur[1], bcur[2], bcur[3]),
                                 make_float4(bcur[4], bcur[5], bcur[6], bcur[7]));
            acc4 = __builtin_amdgcn_mfma_f32_16x16x32_bf16(af, bf, acc4, 0, 0, 0);
        }

        if (gq < 2) {
            const int dcol = h * DK + w * 16 + cr;
#pragma unroll
            for (int reg = 0; reg < 4; ++reg) {
                const int r = gq * 4 + reg;
                out[((size_t)b * S + q0 + r) * D + dcol] = acc4[reg] * rowinv[r];
            }
        }
    }
}

extern "C" void kernel_launch(void* const* d_in, const int* in_sizes, int n_in,
                              void* d_out, int out_size, void* d_ws, size_t ws_size,
                              hipStream_t stream) {
    const float* Qi = (const float*)d_in[1];
    const float* Ki = (const float*)d_in[2];
    const float* Vi = (const float*)d_in[3];
    const float* Wq = (const float*)d_in[4];
    const float* bq = (const float*)d_in[5];
    const float* Wk = (const float*)d_in[6];
    const float* bk = (const float*)d_in[7];
    const float* Wv = (const float*)d_in[8];
    const float* bv = (const float*)d_in[9];
    float* outp = (float*)d_out;

    float* qws = (float*)d_ws;                       // f32 [B,H,S,DK]
    float* kws = qws + (size_t)NB * NH * S * DK;     // f32 [B,H,DK,S] (transposed)
    float* vws = kws + (size_t)NB * NH * S * DK;     // f32 [B,H,S,DK]

    dim3 gv(D / 64, (NB * S) / 128);
    vproj_kernel<<<gv, 256, 0, stream>>>(Vi, Wv, bv, vws);

    dim3 g1(D / 128, (NB * S) / 128, 2);
    proj_kernel<<<g1, 256, 0, stream>>>(Qi, Ki, Wq, bq, Wk, bk, qws, kws);

    dim3 g2(S / ROWS, NH, NB);
    attn_kernel<<<g2, 256, 0, stream>>>(qws, kws, vws, outp);
}